// Round 1
// baseline (251.718 us; speedup 1.0000x reference)
//
#include <hip/hip_runtime.h>
#include <hip/hip_bf16.h>

#define BB  2
#define CC  64
#define HH  256
#define WW  320
#define NNB 9

typedef unsigned int uint;

// ---------------------------------------------------------------------------
// Kernel 1: transpose [B,C,H,W] fp32 -> [B,H,W,C] bf16 (channel-contiguous)
// LDS-tiled: coalesced reads along W, coalesced writes along C, 65-pad = no
// bank conflicts on the column read.
// ---------------------------------------------------------------------------
__global__ __launch_bounds__(256) void fw_transpose(const float* __restrict__ feat,
                                                    ushort* __restrict__ featT) {
  __shared__ float tile[64][65];
  const int b = blockIdx.z, h = blockIdx.y, w0 = blockIdx.x * 64;
  const int tid = threadIdx.x;
#pragma unroll
  for (int it = 0; it < 16; ++it) {
    int idx = it * 256 + tid;
    int c = idx >> 6, w = idx & 63;
    tile[c][w] = feat[((b * CC + c) * HH + h) * WW + w0 + w];
  }
  __syncthreads();
#pragma unroll
  for (int it = 0; it < 16; ++it) {
    int idx = it * 256 + tid;
    int w = idx >> 6, c = idx & 63;
    __hip_bfloat16 v = __float2bfloat16(tile[c][w]);
    featT[((b * HH + h) * WW + w0 + w) * 64 + c] = *(ushort*)&v;
  }
}

__device__ __forceinline__ float blo(uint u) { return __uint_as_float(u << 16); }
__device__ __forceinline__ float bhi(uint u) { return __uint_as_float(u & 0xffff0000u); }

// ---------------------------------------------------------------------------
// Kernel 2: fused grid_sample + group-correlation + BN-folded MLP + sigmoid.
// One thread per output pixel (b,n,h,w). MODE 0: bf16 [B,H,W,C] transposed
// feature in ws. MODE 1: fallback direct fp32 [B,C,H,W] gathers.
// ---------------------------------------------------------------------------
template <int MODE>
__global__ __launch_bounds__(256) void fw_main(
    const float* __restrict__ feat, const ushort* __restrict__ featT,
    const float* __restrict__ grid,
    const float* __restrict__ conv0_w, const float* __restrict__ bn0_g,
    const float* __restrict__ bn0_b, const float* __restrict__ bn0_m,
    const float* __restrict__ bn0_v,
    const float* __restrict__ conv1_w, const float* __restrict__ bn1_g,
    const float* __restrict__ bn1_b, const float* __restrict__ bn1_m,
    const float* __restrict__ bn1_v,
    const float* __restrict__ sim_w, const float* __restrict__ sim_b,
    float* __restrict__ out) {
  // ---- fold BN into affine weights, once per block, into LDS -------------
  __shared__ float sW0[16 * 8], sB0[16], sW1[8 * 16], sB1[8], sSW[8], sSB[1];
  const int tid = threadIdx.x;
  if (tid < 16) {
    float a = bn0_g[tid] * rsqrtf(bn0_v[tid] + 1e-5f);
    sB0[tid] = bn0_b[tid] - bn0_m[tid] * a;
#pragma unroll
    for (int g = 0; g < 8; ++g) sW0[tid * 8 + g] = conv0_w[tid * 8 + g] * a;
  } else if (tid < 24) {
    int o = tid - 16;
    float a = bn1_g[o] * rsqrtf(bn1_v[o] + 1e-5f);
    sB1[o] = bn1_b[o] - bn1_m[o] * a;
#pragma unroll
    for (int c = 0; c < 16; ++c) sW1[o * 16 + c] = conv1_w[o * 16 + c] * a;
  } else if (tid < 32) {
    sSW[tid - 24] = sim_w[tid - 24];
    if (tid == 31) sSB[0] = sim_b[0];
  }
  __syncthreads();

  const int t = blockIdx.x * 256 + tid;  // grid sized exactly: no bounds check
  const int w = t % WW;
  const int tmp = t / WW;
  const int h = tmp & (HH - 1);
  const int nb = tmp >> 8;          // b*9 + n
  const int n = nb % NNB;
  const int b = nb / NNB;

  // ---- grid -> bilinear corners (border padding, align_corners=False) ----
  const float2 g2 =
      *(const float2*)(grid + (size_t)2 * (((size_t)(b * (NNB * HH) + n * HH + h)) * WW + w));
  float ix = fminf(fmaxf(((g2.x + 1.0f) * (float)WW - 1.0f) * 0.5f, 0.0f), (float)(WW - 1));
  float iy = fminf(fmaxf(((g2.y + 1.0f) * (float)HH - 1.0f) * 0.5f, 0.0f), (float)(HH - 1));
  float x0f = floorf(ix), y0f = floorf(iy);
  float wx = ix - x0f, wy = iy - y0f;
  int x0 = (int)x0f, y0 = (int)y0f;
  int x1 = min(x0 + 1, WW - 1), y1 = min(y0 + 1, HH - 1);
  float w00 = (1.0f - wx) * (1.0f - wy);
  float w01 = wx * (1.0f - wy);
  float w10 = (1.0f - wx) * wy;
  float w11 = wx * wy;

  float corr[8];

  if (MODE == 0) {
    const ushort* fb = featT + (size_t)b * (HH * WW * 64);
    const uint4* p00 = (const uint4*)(fb + (y0 * WW + x0) * 64);
    const uint4* p01 = (const uint4*)(fb + (y0 * WW + x1) * 64);
    const uint4* p10 = (const uint4*)(fb + (y1 * WW + x0) * 64);
    const uint4* p11 = (const uint4*)(fb + (y1 * WW + x1) * 64);
    const uint4* pr  = (const uint4*)(fb + (h * WW + w) * 64);
#pragma unroll
    for (int g = 0; g < 8; ++g) {
      uint4 va = p00[g], vb = p01[g], vc = p10[g], vd = p11[g], vr = pr[g];
      const uint* ua = (const uint*)&va;
      const uint* ub = (const uint*)&vb;
      const uint* uc = (const uint*)&vc;
      const uint* ud = (const uint*)&vd;
      const uint* ur = (const uint*)&vr;
      float acc = 0.0f;
#pragma unroll
      for (int k = 0; k < 4; ++k) {
        float s0 = w00 * blo(ua[k]) + w01 * blo(ub[k]) + w10 * blo(uc[k]) + w11 * blo(ud[k]);
        acc += s0 * blo(ur[k]);
        float s1 = w00 * bhi(ua[k]) + w01 * bhi(ub[k]) + w10 * bhi(uc[k]) + w11 * bhi(ud[k]);
        acc += s1 * bhi(ur[k]);
      }
      corr[g] = acc * 0.125f;
    }
  } else {
    const float* fb = feat + (size_t)b * (CC * HH * WW);
#pragma unroll
    for (int g = 0; g < 8; ++g) {
      float acc = 0.0f;
      for (int ch = 0; ch < 8; ++ch) {
        const float* fc = fb + (size_t)(g * 8 + ch) * (HH * WW);
        float s = w00 * fc[y0 * WW + x0] + w01 * fc[y0 * WW + x1] +
                  w10 * fc[y1 * WW + x0] + w11 * fc[y1 * WW + x1];
        acc += s * fc[h * WW + w];
      }
      corr[g] = acc * 0.125f;
    }
  }

  // ---- tiny MLP (BN folded) + sigmoid ------------------------------------
  float h0v[16];
#pragma unroll
  for (int o = 0; o < 16; ++o) {
    float s = sB0[o];
#pragma unroll
    for (int g = 0; g < 8; ++g) s += sW0[o * 8 + g] * corr[g];
    h0v[o] = fmaxf(s, 0.0f);
  }
  float h1v[8];
#pragma unroll
  for (int o = 0; o < 8; ++o) {
    float s = sB1[o];
#pragma unroll
    for (int c = 0; c < 16; ++c) s += sW1[o * 16 + c] * h0v[c];
    h1v[o] = fmaxf(s, 0.0f);
  }
  float s = sSB[0];
#pragma unroll
  for (int c = 0; c < 8; ++c) s += sSW[c] * h1v[c];

  out[t] = 1.0f / (1.0f + __expf(-s));
}

// ---------------------------------------------------------------------------
extern "C" void kernel_launch(void* const* d_in, const int* in_sizes, int n_in,
                              void* d_out, int out_size, void* d_ws, size_t ws_size,
                              hipStream_t stream) {
  const float* ref_feature = (const float*)d_in[0];
  const float* grid    = (const float*)d_in[1];
  const float* conv0_w = (const float*)d_in[2];
  const float* bn0_g   = (const float*)d_in[3];
  const float* bn0_b   = (const float*)d_in[4];
  const float* bn0_m   = (const float*)d_in[5];
  const float* bn0_v   = (const float*)d_in[6];
  const float* conv1_w = (const float*)d_in[7];
  const float* bn1_g   = (const float*)d_in[8];
  const float* bn1_b   = (const float*)d_in[9];
  const float* bn1_m   = (const float*)d_in[10];
  const float* bn1_v   = (const float*)d_in[11];
  const float* sim_w   = (const float*)d_in[12];
  const float* sim_b   = (const float*)d_in[13];
  float* out = (float*)d_out;

  const int total = BB * NNB * HH * WW;         // 1,474,560
  const int blocks = total / 256;               // 5760, exact
  const size_t needT = (size_t)BB * HH * WW * 64 * sizeof(ushort);  // ~21 MB

  if (ws_size >= needT) {
    ushort* featT = (ushort*)d_ws;
    fw_transpose<<<dim3(WW / 64, HH, BB), 256, 0, stream>>>(ref_feature, featT);
    fw_main<0><<<blocks, 256, 0, stream>>>(ref_feature, featT, grid,
        conv0_w, bn0_g, bn0_b, bn0_m, bn0_v,
        conv1_w, bn1_g, bn1_b, bn1_m, bn1_v, sim_w, sim_b, out);
  } else {
    fw_main<1><<<blocks, 256, 0, stream>>>(ref_feature, nullptr, grid,
        conv0_w, bn0_g, bn0_b, bn0_m, bn0_v,
        conv1_w, bn1_g, bn1_b, bn1_m, bn1_v, sim_w, sim_b, out);
  }
}

// Round 3
// 181.994 us; speedup vs baseline: 1.3831x; 1.3831x over previous
//
#include <hip/hip_runtime.h>
#include <hip/hip_bf16.h>

#define BB  2
#define CC  64
#define HH  256
#define WW  320
#define NNB 9
#define PIX_PER_B (NNB * HH * WW)   // 737280
#define PIX_PER_BLOCK 128           // 256 threads, 2 lanes per pixel

typedef unsigned int uint;

// ---------------------------------------------------------------------------
// Kernel 1: transpose [B,C,H,W] fp32 -> [B,H,W,C] bf16 (channel-contiguous)
// ---------------------------------------------------------------------------
__global__ __launch_bounds__(256) void fw_transpose(const float* __restrict__ feat,
                                                    ushort* __restrict__ featT) {
  __shared__ float tile[64][65];
  const int b = blockIdx.z, h = blockIdx.y, w0 = blockIdx.x * 64;
  const int tid = threadIdx.x;
#pragma unroll
  for (int it = 0; it < 16; ++it) {
    int idx = it * 256 + tid;
    int c = idx >> 6, w = idx & 63;
    tile[c][w] = feat[((b * CC + c) * HH + h) * WW + w0 + w];
  }
  __syncthreads();
#pragma unroll
  for (int it = 0; it < 16; ++it) {
    int idx = it * 256 + tid;
    int w = idx >> 6, c = idx & 63;
    __hip_bfloat16 v = __float2bfloat16(tile[c][w]);
    featT[((b * HH + h) * WW + w0 + w) * 64 + c] = *(ushort*)&v;
  }
}

__device__ __forceinline__ float blo(uint u) { return __uint_as_float(u << 16); }
__device__ __forceinline__ float bhi(uint u) { return __uint_as_float(u & 0xffff0000u); }

// ---------------------------------------------------------------------------
// Weight folding into LDS (BN folded to affine), shared by both main kernels.
// ---------------------------------------------------------------------------
#define FOLD_WEIGHTS()                                                         \
  __shared__ float sW0[16 * 8], sB0[16], sW1[8 * 16], sB1[8], sSW[8], sSB[1];  \
  {                                                                            \
    const int tt = threadIdx.x;                                                \
    if (tt < 16) {                                                             \
      float a = bn0_g[tt] * rsqrtf(bn0_v[tt] + 1e-5f);                         \
      sB0[tt] = bn0_b[tt] - bn0_m[tt] * a;                                     \
      _Pragma("unroll") for (int g = 0; g < 8; ++g)                            \
          sW0[tt * 8 + g] = conv0_w[tt * 8 + g] * a;                           \
    } else if (tt < 24) {                                                      \
      int o = tt - 16;                                                         \
      float a = bn1_g[o] * rsqrtf(bn1_v[o] + 1e-5f);                           \
      sB1[o] = bn1_b[o] - bn1_m[o] * a;                                        \
      _Pragma("unroll") for (int c = 0; c < 16; ++c)                           \
          sW1[o * 16 + c] = conv1_w[o * 16 + c] * a;                           \
    } else if (tt < 32) {                                                      \
      sSW[tt - 24] = sim_w[tt - 24];                                           \
      if (tt == 31) sSB[0] = sim_b[0];                                         \
    }                                                                          \
  }                                                                            \
  __syncthreads();

#define WARGS                                                                   \
  const float* __restrict__ conv0_w, const float* __restrict__ bn0_g,           \
  const float* __restrict__ bn0_b, const float* __restrict__ bn0_m,             \
  const float* __restrict__ bn0_v, const float* __restrict__ conv1_w,           \
  const float* __restrict__ bn1_g, const float* __restrict__ bn1_b,             \
  const float* __restrict__ bn1_m, const float* __restrict__ bn1_v,             \
  const float* __restrict__ sim_w, const float* __restrict__ sim_b

// ---------------------------------------------------------------------------
// Kernel 2 (fast path): 2 lanes per pixel (channel split), all gathers
// hoisted, XCD-pinned batches.
//   lanes L and L+32 of a wave handle the same pixel:
//   half 0 -> groups 0..3 (channels 0..31), half 1 -> groups 4..7.
// ---------------------------------------------------------------------------
__global__ __launch_bounds__(256, 4) void fw_main2(
    const ushort* __restrict__ featT, const float* __restrict__ grid,
    WARGS, float* __restrict__ out) {
  FOLD_WEIGHTS();

  // XCD pinning: round-robin dispatch sends block i to XCD i%8.
  // XCDs 0..3 -> batch 0, XCDs 4..7 -> batch 1 (bijective remap).
  // 11520 blocks total: blk>>3 in [0,1440), lblk = j*4+(xcd&3) in [0,5760).
  const int blk = blockIdx.x;
  const int xcd = blk & 7;
  const int j = blk >> 3;
  const int b = xcd >> 2;
  const int lblk = j * 4 + (xcd & 3);

  const int tid = threadIdx.x;
  const int lane = tid & 63;
  const int wid = tid >> 6;                // wave in block, 0..3
  const int half = lane >> 5;              // 0: groups 0..3, 1: groups 4..7
  const int pix = lblk * PIX_PER_BLOCK + wid * 32 + (lane & 31);  // [0, 737280)

  const int w = pix % WW;
  const int t2 = pix / WW;
  const int h = t2 & (HH - 1);
  const int n = t2 >> 8;                   // 0..8

  // ---- grid -> bilinear corners (border padding, align_corners=False) ----
  const float2 g2 =
      *(const float2*)(grid + (size_t)2 * (((size_t)((b * NNB + n) * HH + h)) * WW + w));
  float ix = fminf(fmaxf(((g2.x + 1.0f) * (float)WW - 1.0f) * 0.5f, 0.0f), (float)(WW - 1));
  float iy = fminf(fmaxf(((g2.y + 1.0f) * (float)HH - 1.0f) * 0.5f, 0.0f), (float)(HH - 1));
  float x0f = floorf(ix), y0f = floorf(iy);
  float wx = ix - x0f, wy = iy - y0f;
  int x0 = (int)x0f, y0 = (int)y0f;
  int x1 = min(x0 + 1, WW - 1), y1 = min(y0 + 1, HH - 1);
  float w00 = (1.0f - wx) * (1.0f - wy);
  float w01 = wx * (1.0f - wy);
  float w10 = (1.0f - wx) * wy;
  float w11 = wx * wy;

  // ---- hoisted gathers: 5 streams x 4 uint4 (64 B each = 4 groups) -------
  const ushort* fb = featT + (size_t)b * (HH * WW * 64) + half * 32;
  const uint4* p00 = (const uint4*)(fb + (y0 * WW + x0) * 64);
  const uint4* p01 = (const uint4*)(fb + (y0 * WW + x1) * 64);
  const uint4* p10 = (const uint4*)(fb + (y1 * WW + x0) * 64);
  const uint4* p11 = (const uint4*)(fb + (y1 * WW + x1) * 64);
  const uint4* pr  = (const uint4*)(fb + (h * WW + w) * 64);

  uint4 A[4], Bv[4], Cv[4], Dv[4], Rv[4];
#pragma unroll
  for (int k = 0; k < 4; ++k) A[k] = p00[k];
#pragma unroll
  for (int k = 0; k < 4; ++k) Bv[k] = p01[k];
#pragma unroll
  for (int k = 0; k < 4; ++k) Cv[k] = p10[k];
#pragma unroll
  for (int k = 0; k < 4; ++k) Dv[k] = p11[k];
#pragma unroll
  for (int k = 0; k < 4; ++k) Rv[k] = pr[k];

  // ---- 4 local group correlations ----------------------------------------
  float c4[4];
#pragma unroll
  for (int gg = 0; gg < 4; ++gg) {
    const uint* ua = (const uint*)&A[gg];
    const uint* ub = (const uint*)&Bv[gg];
    const uint* uc = (const uint*)&Cv[gg];
    const uint* ud = (const uint*)&Dv[gg];
    const uint* ur = (const uint*)&Rv[gg];
    float acc = 0.0f;
#pragma unroll
    for (int k = 0; k < 4; ++k) {
      float s0 = w00 * blo(ua[k]) + w01 * blo(ub[k]) + w10 * blo(uc[k]) + w11 * blo(ud[k]);
      acc += s0 * blo(ur[k]);
      float s1 = w00 * bhi(ua[k]) + w01 * bhi(ub[k]) + w10 * bhi(uc[k]) + w11 * bhi(ud[k]);
      acc += s1 * bhi(ur[k]);
    }
    c4[gg] = acc * 0.125f;
  }

  // ---- exchange the other half's 4 correlations --------------------------
  float corr[8];
#pragma unroll
  for (int k = 0; k < 4; ++k) {
    float o = __shfl_xor(c4[k], 32);
    corr[half * 4 + k] = c4[k];
    corr[(1 - half) * 4 + k] = o;
  }

  // ---- tiny MLP (BN folded) + sigmoid (duplicated across both halves) ----
  float h0v[16];
#pragma unroll
  for (int o = 0; o < 16; ++o) {
    float s = sB0[o];
#pragma unroll
    for (int g = 0; g < 8; ++g) s += sW0[o * 8 + g] * corr[g];
    h0v[o] = fmaxf(s, 0.0f);
  }
  float h1v[8];
#pragma unroll
  for (int o = 0; o < 8; ++o) {
    float s = sB1[o];
#pragma unroll
    for (int c = 0; c < 16; ++c) s += sW1[o * 16 + c] * h0v[c];
    h1v[o] = fmaxf(s, 0.0f);
  }
  float s = sSB[0];
#pragma unroll
  for (int c = 0; c < 8; ++c) s += sSW[c] * h1v[c];

  if (half == 0) out[(size_t)b * PIX_PER_B + pix] = 1.0f / (1.0f + __expf(-s));
}

// ---------------------------------------------------------------------------
// Fallback (no workspace): 1 thread per pixel, direct fp32 gathers.
// ---------------------------------------------------------------------------
__global__ __launch_bounds__(256) void fw_main_fallback(
    const float* __restrict__ feat, const float* __restrict__ grid,
    WARGS, float* __restrict__ out) {
  FOLD_WEIGHTS();
  const int t = blockIdx.x * 256 + threadIdx.x;
  const int w = t % WW;
  const int tmp = t / WW;
  const int h = tmp & (HH - 1);
  const int nb = tmp >> 8;
  const int n = nb % NNB;
  const int b = nb / NNB;

  const float2 g2 =
      *(const float2*)(grid + (size_t)2 * (((size_t)((b * NNB + n) * HH + h)) * WW + w));
  float ix = fminf(fmaxf(((g2.x + 1.0f) * (float)WW - 1.0f) * 0.5f, 0.0f), (float)(WW - 1));
  float iy = fminf(fmaxf(((g2.y + 1.0f) * (float)HH - 1.0f) * 0.5f, 0.0f), (float)(HH - 1));
  float x0f = floorf(ix), y0f = floorf(iy);
  float wx = ix - x0f, wy = iy - y0f;
  int x0 = (int)x0f, y0 = (int)y0f;
  int x1 = min(x0 + 1, WW - 1), y1 = min(y0 + 1, HH - 1);
  float w00 = (1.0f - wx) * (1.0f - wy), w01 = wx * (1.0f - wy);
  float w10 = (1.0f - wx) * wy, w11 = wx * wy;

  float corr[8];
  const float* fb = feat + (size_t)b * (CC * HH * WW);
#pragma unroll
  for (int g = 0; g < 8; ++g) {
    float acc = 0.0f;
    for (int ch = 0; ch < 8; ++ch) {
      const float* fc = fb + (size_t)(g * 8 + ch) * (HH * WW);
      float sv = w00 * fc[y0 * WW + x0] + w01 * fc[y0 * WW + x1] +
                 w10 * fc[y1 * WW + x0] + w11 * fc[y1 * WW + x1];
      acc += sv * fc[h * WW + w];
    }
    corr[g] = acc * 0.125f;
  }

  float h0v[16];
#pragma unroll
  for (int o = 0; o < 16; ++o) {
    float s = sB0[o];
#pragma unroll
    for (int g = 0; g < 8; ++g) s += sW0[o * 8 + g] * corr[g];
    h0v[o] = fmaxf(s, 0.0f);
  }
  float h1v[8];
#pragma unroll
  for (int o = 0; o < 8; ++o) {
    float s = sB1[o];
#pragma unroll
    for (int c = 0; c < 16; ++c) s += sW1[o * 16 + c] * h0v[c];
    h1v[o] = fmaxf(s, 0.0f);
  }
  float s = sSB[0];
#pragma unroll
  for (int c = 0; c < 8; ++c) s += sSW[c] * h1v[c];
  out[t] = 1.0f / (1.0f + __expf(-s));
}

// ---------------------------------------------------------------------------
extern "C" void kernel_launch(void* const* d_in, const int* in_sizes, int n_in,
                              void* d_out, int out_size, void* d_ws, size_t ws_size,
                              hipStream_t stream) {
  const float* ref_feature = (const float*)d_in[0];
  const float* grid    = (const float*)d_in[1];
  const float* conv0_w = (const float*)d_in[2];
  const float* bn0_g   = (const float*)d_in[3];
  const float* bn0_b   = (const float*)d_in[4];
  const float* bn0_m   = (const float*)d_in[5];
  const float* bn0_v   = (const float*)d_in[6];
  const float* conv1_w = (const float*)d_in[7];
  const float* bn1_g   = (const float*)d_in[8];
  const float* bn1_b   = (const float*)d_in[9];
  const float* bn1_m   = (const float*)d_in[10];
  const float* bn1_v   = (const float*)d_in[11];
  const float* sim_w   = (const float*)d_in[12];
  const float* sim_b   = (const float*)d_in[13];
  float* out = (float*)d_out;

  const size_t needT = (size_t)BB * HH * WW * 64 * sizeof(ushort);  // ~21 MB

  if (ws_size >= needT) {
    ushort* featT = (ushort*)d_ws;
    fw_transpose<<<dim3(WW / 64, HH, BB), 256, 0, stream>>>(ref_feature, featT);
    // 128 pixels per block (256 threads, 2 lanes/pixel):
    // 1,474,560 / 128 = 11,520 blocks.
    const int blocks2 = BB * PIX_PER_B / PIX_PER_BLOCK;
    fw_main2<<<blocks2, 256, 0, stream>>>(featT, grid,
        conv0_w, bn0_g, bn0_b, bn0_m, bn0_v,
        conv1_w, bn1_g, bn1_b, bn1_m, bn1_v, sim_w, sim_b, out);
  } else {
    fw_main_fallback<<<BB * PIX_PER_B / 256, 256, 0, stream>>>(ref_feature, grid,
        conv0_w, bn0_g, bn0_b, bn0_m, bn0_v,
        conv1_w, bn1_g, bn1_b, bn1_m, bn1_v, sim_w, sim_b, out);
  }
}

// Round 4
// 142.567 us; speedup vs baseline: 1.7656x; 1.2765x over previous
//
#include <hip/hip_runtime.h>
#include <hip/hip_bf16.h>

#define BB  2
#define CC  64
#define HH  256
#define WW  320
#define NNB 9
#define PIX_PER_B (NNB * HH * WW)   // 737280
#define PIX_PER_BLOCK 128           // 256 threads, 2 lanes per pixel

typedef unsigned int uint;

// ---------------------------------------------------------------------------
// Kernel 1: transpose [B,C,H,W] fp32 -> [B,H,W,C] bf16 (channel-contiguous)
// ---------------------------------------------------------------------------
__global__ __launch_bounds__(256) void fw_transpose(const float* __restrict__ feat,
                                                    ushort* __restrict__ featT) {
  __shared__ float tile[64][65];
  const int b = blockIdx.z, h = blockIdx.y, w0 = blockIdx.x * 64;
  const int tid = threadIdx.x;
#pragma unroll
  for (int it = 0; it < 16; ++it) {
    int idx = it * 256 + tid;
    int c = idx >> 6, w = idx & 63;
    tile[c][w] = feat[((b * CC + c) * HH + h) * WW + w0 + w];
  }
  __syncthreads();
#pragma unroll
  for (int it = 0; it < 16; ++it) {
    int idx = it * 256 + tid;
    int w = idx >> 6, c = idx & 63;
    __hip_bfloat16 v = __float2bfloat16(tile[c][w]);
    featT[((b * HH + h) * WW + w0 + w) * 64 + c] = *(ushort*)&v;
  }
}

__device__ __forceinline__ float blo(uint u) { return __uint_as_float(u << 16); }
__device__ __forceinline__ float bhi(uint u) { return __uint_as_float(u & 0xffff0000u); }

// ---------------------------------------------------------------------------
// Weight folding into LDS (BN folded to affine), shared by both main kernels.
// ---------------------------------------------------------------------------
#define FOLD_WEIGHTS()                                                         \
  __shared__ float sW0[16 * 8], sB0[16], sW1[8 * 16], sB1[8], sSW[8], sSB[1];  \
  {                                                                            \
    const int tt = threadIdx.x;                                                \
    if (tt < 16) {                                                             \
      float a = bn0_g[tt] * rsqrtf(bn0_v[tt] + 1e-5f);                         \
      sB0[tt] = bn0_b[tt] - bn0_m[tt] * a;                                     \
      _Pragma("unroll") for (int g = 0; g < 8; ++g)                            \
          sW0[tt * 8 + g] = conv0_w[tt * 8 + g] * a;                           \
    } else if (tt < 24) {                                                      \
      int o = tt - 16;                                                         \
      float a = bn1_g[o] * rsqrtf(bn1_v[o] + 1e-5f);                           \
      sB1[o] = bn1_b[o] - bn1_m[o] * a;                                        \
      _Pragma("unroll") for (int c = 0; c < 16; ++c)                           \
          sW1[o * 16 + c] = conv1_w[o * 16 + c] * a;                           \
    } else if (tt < 32) {                                                      \
      sSW[tt - 24] = sim_w[tt - 24];                                           \
      if (tt == 31) sSB[0] = sim_b[0];                                         \
    }                                                                          \
  }                                                                            \
  __syncthreads();

#define WARGS                                                                   \
  const float* __restrict__ conv0_w, const float* __restrict__ bn0_g,           \
  const float* __restrict__ bn0_b, const float* __restrict__ bn0_m,             \
  const float* __restrict__ bn0_v, const float* __restrict__ conv1_w,           \
  const float* __restrict__ bn1_g, const float* __restrict__ bn1_b,             \
  const float* __restrict__ bn1_m, const float* __restrict__ bn1_v,             \
  const float* __restrict__ sim_w, const float* __restrict__ sim_b

// ---------------------------------------------------------------------------
// Kernel 2 (fast path): 2 lanes per pixel (channel split), all gathers
// hoisted, XCD-pinned batches. NOTE: plain __launch_bounds__(256) — the
// (256,4) min-waves hint made the allocator target 64 VGPRs and spill
// ~16 dwords/thread to scratch (round-3: WRITE_SIZE 183 MB vs 5.9 MB out).
// ---------------------------------------------------------------------------
__global__ __launch_bounds__(256) void fw_main2(
    const ushort* __restrict__ featT, const float* __restrict__ grid,
    WARGS, float* __restrict__ out) {
  FOLD_WEIGHTS();

  // XCD pinning: round-robin dispatch sends block i to XCD i%8.
  // XCDs 0..3 -> batch 0, XCDs 4..7 -> batch 1 (bijective remap).
  const int blk = blockIdx.x;
  const int xcd = blk & 7;
  const int j = blk >> 3;
  const int b = xcd >> 2;
  const int lblk = j * 4 + (xcd & 3);

  const int tid = threadIdx.x;
  const int lane = tid & 63;
  const int wid = tid >> 6;                // wave in block, 0..3
  const int half = lane >> 5;              // 0: groups 0..3, 1: groups 4..7
  const int pix = lblk * PIX_PER_BLOCK + wid * 32 + (lane & 31);  // [0, 737280)

  const int w = pix % WW;
  const int t2 = pix / WW;
  const int h = t2 & (HH - 1);
  const int n = t2 >> 8;                   // 0..8

  // ---- grid -> bilinear corners (border padding, align_corners=False) ----
  const float2 g2 =
      *(const float2*)(grid + (size_t)2 * (((size_t)((b * NNB + n) * HH + h)) * WW + w));
  float ix = fminf(fmaxf(((g2.x + 1.0f) * (float)WW - 1.0f) * 0.5f, 0.0f), (float)(WW - 1));
  float iy = fminf(fmaxf(((g2.y + 1.0f) * (float)HH - 1.0f) * 0.5f, 0.0f), (float)(HH - 1));
  float x0f = floorf(ix), y0f = floorf(iy);
  float wx = ix - x0f, wy = iy - y0f;
  int x0 = (int)x0f, y0 = (int)y0f;
  int x1 = min(x0 + 1, WW - 1), y1 = min(y0 + 1, HH - 1);
  float w00 = (1.0f - wx) * (1.0f - wy);
  float w01 = wx * (1.0f - wy);
  float w10 = (1.0f - wx) * wy;
  float w11 = wx * wy;

  // ---- hoisted gathers: 5 streams x 4 uint4 (64 B each = 4 groups) -------
  const ushort* fb = featT + (size_t)b * (HH * WW * 64) + half * 32;
  const uint4* p00 = (const uint4*)(fb + (y0 * WW + x0) * 64);
  const uint4* p01 = (const uint4*)(fb + (y0 * WW + x1) * 64);
  const uint4* p10 = (const uint4*)(fb + (y1 * WW + x0) * 64);
  const uint4* p11 = (const uint4*)(fb + (y1 * WW + x1) * 64);
  const uint4* pr  = (const uint4*)(fb + (h * WW + w) * 64);

  uint4 A[4], Bv[4], Cv[4], Dv[4], Rv[4];
#pragma unroll
  for (int k = 0; k < 4; ++k) A[k] = p00[k];
#pragma unroll
  for (int k = 0; k < 4; ++k) Bv[k] = p01[k];
#pragma unroll
  for (int k = 0; k < 4; ++k) Cv[k] = p10[k];
#pragma unroll
  for (int k = 0; k < 4; ++k) Dv[k] = p11[k];
#pragma unroll
  for (int k = 0; k < 4; ++k) Rv[k] = pr[k];

  // ---- 4 local group correlations ----------------------------------------
  float c4[4];
#pragma unroll
  for (int gg = 0; gg < 4; ++gg) {
    const uint* ua = (const uint*)&A[gg];
    const uint* ub = (const uint*)&Bv[gg];
    const uint* uc = (const uint*)&Cv[gg];
    const uint* ud = (const uint*)&Dv[gg];
    const uint* ur = (const uint*)&Rv[gg];
    float acc = 0.0f;
#pragma unroll
    for (int k = 0; k < 4; ++k) {
      float s0 = w00 * blo(ua[k]) + w01 * blo(ub[k]) + w10 * blo(uc[k]) + w11 * blo(ud[k]);
      acc += s0 * blo(ur[k]);
      float s1 = w00 * bhi(ua[k]) + w01 * bhi(ub[k]) + w10 * bhi(uc[k]) + w11 * bhi(ud[k]);
      acc += s1 * bhi(ur[k]);
    }
    c4[gg] = acc * 0.125f;
  }

  // ---- exchange the other half's 4 correlations --------------------------
  float corr[8];
#pragma unroll
  for (int k = 0; k < 4; ++k) {
    float o = __shfl_xor(c4[k], 32);
    corr[half * 4 + k] = c4[k];
    corr[(1 - half) * 4 + k] = o;
  }

  // ---- tiny MLP (BN folded) + sigmoid (duplicated across both halves) ----
  float h0v[16];
#pragma unroll
  for (int o = 0; o < 16; ++o) {
    float s = sB0[o];
#pragma unroll
    for (int g = 0; g < 8; ++g) s += sW0[o * 8 + g] * corr[g];
    h0v[o] = fmaxf(s, 0.0f);
  }
  float h1v[8];
#pragma unroll
  for (int o = 0; o < 8; ++o) {
    float s = sB1[o];
#pragma unroll
    for (int c = 0; c < 16; ++c) s += sW1[o * 16 + c] * h0v[c];
    h1v[o] = fmaxf(s, 0.0f);
  }
  float s = sSB[0];
#pragma unroll
  for (int c = 0; c < 8; ++c) s += sSW[c] * h1v[c];

  if (half == 0) out[(size_t)b * PIX_PER_B + pix] = 1.0f / (1.0f + __expf(-s));
}

// ---------------------------------------------------------------------------
// Fallback (no workspace): 1 thread per pixel, direct fp32 gathers.
// ---------------------------------------------------------------------------
__global__ __launch_bounds__(256) void fw_main_fallback(
    const float* __restrict__ feat, const float* __restrict__ grid,
    WARGS, float* __restrict__ out) {
  FOLD_WEIGHTS();
  const int t = blockIdx.x * 256 + threadIdx.x;
  const int w = t % WW;
  const int tmp = t / WW;
  const int h = tmp & (HH - 1);
  const int nb = tmp >> 8;
  const int n = nb % NNB;
  const int b = nb / NNB;

  const float2 g2 =
      *(const float2*)(grid + (size_t)2 * (((size_t)((b * NNB + n) * HH + h)) * WW + w));
  float ix = fminf(fmaxf(((g2.x + 1.0f) * (float)WW - 1.0f) * 0.5f, 0.0f), (float)(WW - 1));
  float iy = fminf(fmaxf(((g2.y + 1.0f) * (float)HH - 1.0f) * 0.5f, 0.0f), (float)(HH - 1));
  float x0f = floorf(ix), y0f = floorf(iy);
  float wx = ix - x0f, wy = iy - y0f;
  int x0 = (int)x0f, y0 = (int)y0f;
  int x1 = min(x0 + 1, WW - 1), y1 = min(y0 + 1, HH - 1);
  float w00 = (1.0f - wx) * (1.0f - wy), w01 = wx * (1.0f - wy);
  float w10 = (1.0f - wx) * wy, w11 = wx * wy;

  float corr[8];
  const float* fb = feat + (size_t)b * (CC * HH * WW);
#pragma unroll
  for (int g = 0; g < 8; ++g) {
    float acc = 0.0f;
    for (int ch = 0; ch < 8; ++ch) {
      const float* fc = fb + (size_t)(g * 8 + ch) * (HH * WW);
      float sv = w00 * fc[y0 * WW + x0] + w01 * fc[y0 * WW + x1] +
                 w10 * fc[y1 * WW + x0] + w11 * fc[y1 * WW + x1];
      acc += sv * fc[h * WW + w];
    }
    corr[g] = acc * 0.125f;
  }

  float h0v[16];
#pragma unroll
  for (int o = 0; o < 16; ++o) {
    float s = sB0[o];
#pragma unroll
    for (int g = 0; g < 8; ++g) s += sW0[o * 8 + g] * corr[g];
    h0v[o] = fmaxf(s, 0.0f);
  }
  float h1v[8];
#pragma unroll
  for (int o = 0; o < 8; ++o) {
    float s = sB1[o];
#pragma unroll
    for (int c = 0; c < 16; ++c) s += sW1[o * 16 + c] * h0v[c];
    h1v[o] = fmaxf(s, 0.0f);
  }
  float s = sSB[0];
#pragma unroll
  for (int c = 0; c < 8; ++c) s += sSW[c] * h1v[c];
  out[t] = 1.0f / (1.0f + __expf(-s));
}

// ---------------------------------------------------------------------------
extern "C" void kernel_launch(void* const* d_in, const int* in_sizes, int n_in,
                              void* d_out, int out_size, void* d_ws, size_t ws_size,
                              hipStream_t stream) {
  const float* ref_feature = (const float*)d_in[0];
  const float* grid    = (const float*)d_in[1];
  const float* conv0_w = (const float*)d_in[2];
  const float* bn0_g   = (const float*)d_in[3];
  const float* bn0_b   = (const float*)d_in[4];
  const float* bn0_m   = (const float*)d_in[5];
  const float* bn0_v   = (const float*)d_in[6];
  const float* conv1_w = (const float*)d_in[7];
  const float* bn1_g   = (const float*)d_in[8];
  const float* bn1_b   = (const float*)d_in[9];
  const float* bn1_m   = (const float*)d_in[10];
  const float* bn1_v   = (const float*)d_in[11];
  const float* sim_w   = (const float*)d_in[12];
  const float* sim_b   = (const float*)d_in[13];
  float* out = (float*)d_out;

  const size_t needT = (size_t)BB * HH * WW * 64 * sizeof(ushort);  // ~21 MB

  if (ws_size >= needT) {
    ushort* featT = (ushort*)d_ws;
    fw_transpose<<<dim3(WW / 64, HH, BB), 256, 0, stream>>>(ref_feature, featT);
    // 128 pixels per block (256 threads, 2 lanes/pixel):
    // 1,474,560 / 128 = 11,520 blocks.
    const int blocks2 = BB * PIX_PER_B / PIX_PER_BLOCK;
    fw_main2<<<blocks2, 256, 0, stream>>>(featT, grid,
        conv0_w, bn0_g, bn0_b, bn0_m, bn0_v,
        conv1_w, bn1_g, bn1_b, bn1_m, bn1_v, sim_w, sim_b, out);
  } else {
    fw_main_fallback<<<BB * PIX_PER_B / 256, 256, 0, stream>>>(ref_feature, grid,
        conv0_w, bn0_g, bn0_b, bn0_m, bn0_v,
        conv1_w, bn1_g, bn1_b, bn1_m, bn1_v, sim_w, sim_b, out);
  }
}